// Round 4
// baseline (651.157 us; speedup 1.0000x reference)
//
#include <hip/hip_runtime.h>
#include <hip/hip_cooperative_groups.h>

namespace cg = cooperative_groups;

namespace {

// gaussian kernel, KSIZE=3, SIGMA=1
constexpr float kG0   = 0.27406862f;
constexpr float kG1   = 0.45186276f;
constexpr float kEdge = kG0 + kG1;   // boundary weight-sum (zero padding)

typedef __attribute__((ext_vector_type(8))) short bf16x8;
typedef __attribute__((ext_vector_type(4))) float f32x4;

__device__ __forceinline__ ushort f2bf(float f) {
  union { float f; uint u; } v{f};
  return (ushort)((v.u + 0x7fffu + ((v.u >> 16) & 1u)) >> 16);  // RNE
}

// convert 16 fp32 (4x float4) -> 16 bf16, store to LDS (two 16B stores)
__device__ __forceinline__ void cvt_store16(const float4 v0, const float4 v1,
                                            const float4 v2, const float4 v3,
                                            short* dst) {
  bf16x8 lo, hi;
  lo[0] = (short)f2bf(v0.x); lo[1] = (short)f2bf(v0.y);
  lo[2] = (short)f2bf(v0.z); lo[3] = (short)f2bf(v0.w);
  lo[4] = (short)f2bf(v1.x); lo[5] = (short)f2bf(v1.y);
  lo[6] = (short)f2bf(v1.z); lo[7] = (short)f2bf(v1.w);
  hi[0] = (short)f2bf(v2.x); hi[1] = (short)f2bf(v2.y);
  hi[2] = (short)f2bf(v2.z); hi[3] = (short)f2bf(v2.w);
  hi[4] = (short)f2bf(v3.x); hi[5] = (short)f2bf(v3.y);
  hi[6] = (short)f2bf(v3.z); hi[7] = (short)f2bf(v3.w);
  *(bf16x8*)dst = lo;
  *(bf16x8*)(dst + 8) = hi;
}

// Persistent cooperative kernel. Phases:
//  1. proj[1536][512] (bf16) = ((enc_h|dec_h) @ (W_enc|W_dec)^T + b) * rowmask
//  2. term[1536][512] (f32)  = proj @ (Wf_e|Wf_d)^T      (rows<1024: enc, else dec)
//  3. dec_blur/enc_blur = 3-tap blur of term rows along d / e
//  4. out.grid = dec_term[b,d,:] + enc_term[b,e,:] + b_fus   (256 MB write)
//     out.mask = ||dec_blur*sE + enc_blur*sD + b_fus*sE*sD|| > 0   (concurrent)
__global__ __launch_bounds__(256, 3)
void fused(const float* __restrict__ enc_h, const float* __restrict__ dec_h,
           const float* __restrict__ enc_m, const float* __restrict__ dec_m,
           const float* __restrict__ W_enc, const float* __restrict__ b_enc,
           const float* __restrict__ W_dec, const float* __restrict__ b_dec,
           const float* __restrict__ W_fus, const float* __restrict__ b_fus,
           float* __restrict__ out, ushort* __restrict__ proj,
           float* __restrict__ term, float* __restrict__ dec_blur,
           float* __restrict__ enc_blur) {
  cg::grid_group grid = cg::this_grid();
  __shared__ short As[64][72], Bs[64][72];
  const int tid = threadIdx.x;
  const int wid = tid >> 6, lane = tid & 63;
  const int srow = tid >> 2, sc = tid & 3;       // staging: row, 16-elem chunk
  const int wr = (wid >> 1) * 32, wc = (wid & 1) * 32;
  const int r16 = lane & 15, kb = lane >> 4;     // MFMA frag coords (verified R3)

  // ===== phase 1: GEMM1 -> proj bf16 (24 row-tiles x 8 col-tiles, K=1024) =====
  for (int t = blockIdx.x; t < 192; t += gridDim.x) {
    const int row0 = (t >> 3) * 64, col0 = (t & 7) * 64;
    const bool enc = row0 < 1024;
    const float* Ap = (enc ? enc_h + (size_t)row0 * 1024
                           : dec_h + (size_t)(row0 - 1024) * 1024)
                      + (size_t)srow * 1024 + sc * 16;
    const float* Bp = (enc ? W_enc : W_dec)
                      + (size_t)(col0 + srow) * 1024 + sc * 16;
    f32x4 acc[2][2] = {};
    for (int k0 = 0; k0 < 1024; k0 += 64) {
      const float4 a0 = *(const float4*)(Ap + k0);
      const float4 a1 = *(const float4*)(Ap + k0 + 4);
      const float4 a2 = *(const float4*)(Ap + k0 + 8);
      const float4 a3 = *(const float4*)(Ap + k0 + 12);
      const float4 b0 = *(const float4*)(Bp + k0);
      const float4 b1 = *(const float4*)(Bp + k0 + 4);
      const float4 b2 = *(const float4*)(Bp + k0 + 8);
      const float4 b3 = *(const float4*)(Bp + k0 + 12);
      __syncthreads();
      cvt_store16(a0, a1, a2, a3, &As[srow][sc * 16]);
      cvt_store16(b0, b1, b2, b3, &Bs[srow][sc * 16]);
      __syncthreads();
#pragma unroll
      for (int ks = 0; ks < 2; ++ks) {
        const int ko = ks * 32 + kb * 8;
        const bf16x8 fa0 = *(const bf16x8*)&As[wr + r16][ko];
        const bf16x8 fa1 = *(const bf16x8*)&As[wr + 16 + r16][ko];
        const bf16x8 fb0 = *(const bf16x8*)&Bs[wc + r16][ko];
        const bf16x8 fb1 = *(const bf16x8*)&Bs[wc + 16 + r16][ko];
        acc[0][0] = __builtin_amdgcn_mfma_f32_16x16x32_bf16(fa0, fb0, acc[0][0], 0, 0, 0);
        acc[0][1] = __builtin_amdgcn_mfma_f32_16x16x32_bf16(fa0, fb1, acc[0][1], 0, 0, 0);
        acc[1][0] = __builtin_amdgcn_mfma_f32_16x16x32_bf16(fa1, fb0, acc[1][0], 0, 0, 0);
        acc[1][1] = __builtin_amdgcn_mfma_f32_16x16x32_bf16(fa1, fb1, acc[1][1], 0, 0, 0);
      }
    }
    const float* bias = enc ? b_enc : b_dec;
    const float* rm   = enc ? enc_m : (dec_m - 1024);
#pragma unroll
    for (int i = 0; i < 2; ++i)
#pragma unroll
      for (int j = 0; j < 2; ++j)
#pragma unroll
        for (int q = 0; q < 4; ++q) {
          const int r = row0 + wr + i * 16 + kb * 4 + q;
          const int c = col0 + wc + j * 16 + r16;
          proj[(size_t)r * 512 + c] = f2bf((acc[i][j][q] + bias[c]) * rm[r]);
        }
  }
  grid.sync();

  // ===== phase 2: GEMM2 -> term f32 (K=512; B cols offset 512 for dec rows) =====
  for (int t = blockIdx.x; t < 192; t += gridDim.x) {
    const int row0 = (t >> 3) * 64, col0 = (t & 7) * 64;
    const bool enc = row0 < 1024;
    const short* Ap = (const short*)proj + (size_t)(row0 + srow) * 512 + sc * 16;
    const float* Bp = W_fus + (size_t)(col0 + srow) * 1024 + (enc ? 0 : 512) + sc * 16;
    f32x4 acc[2][2] = {};
    for (int k0 = 0; k0 < 512; k0 += 64) {
      const bf16x8 alo = *(const bf16x8*)(Ap + k0);
      const bf16x8 ahi = *(const bf16x8*)(Ap + k0 + 8);
      const float4 b0 = *(const float4*)(Bp + k0);
      const float4 b1 = *(const float4*)(Bp + k0 + 4);
      const float4 b2 = *(const float4*)(Bp + k0 + 8);
      const float4 b3 = *(const float4*)(Bp + k0 + 12);
      __syncthreads();
      *(bf16x8*)&As[srow][sc * 16] = alo;
      *(bf16x8*)&As[srow][sc * 16 + 8] = ahi;
      cvt_store16(b0, b1, b2, b3, &Bs[srow][sc * 16]);
      __syncthreads();
#pragma unroll
      for (int ks = 0; ks < 2; ++ks) {
        const int ko = ks * 32 + kb * 8;
        const bf16x8 fa0 = *(const bf16x8*)&As[wr + r16][ko];
        const bf16x8 fa1 = *(const bf16x8*)&As[wr + 16 + r16][ko];
        const bf16x8 fb0 = *(const bf16x8*)&Bs[wc + r16][ko];
        const bf16x8 fb1 = *(const bf16x8*)&Bs[wc + 16 + r16][ko];
        acc[0][0] = __builtin_amdgcn_mfma_f32_16x16x32_bf16(fa0, fb0, acc[0][0], 0, 0, 0);
        acc[0][1] = __builtin_amdgcn_mfma_f32_16x16x32_bf16(fa0, fb1, acc[0][1], 0, 0, 0);
        acc[1][0] = __builtin_amdgcn_mfma_f32_16x16x32_bf16(fa1, fb0, acc[1][0], 0, 0, 0);
        acc[1][1] = __builtin_amdgcn_mfma_f32_16x16x32_bf16(fa1, fb1, acc[1][1], 0, 0, 0);
      }
    }
#pragma unroll
    for (int i = 0; i < 2; ++i)
#pragma unroll
      for (int j = 0; j < 2; ++j)
#pragma unroll
        for (int q = 0; q < 4; ++q) {
          const int r = row0 + wr + i * 16 + kb * 4 + q;
          const int c = col0 + wc + j * 16 + r16;
          term[(size_t)r * 512 + c] = acc[i][j][q];
        }
  }
  grid.sync();

  // ===== phase 3: blur (dec rows along d, enc rows along e) =====
  {
    const float* dterm = term + 524288;  // dec rows start at row 1024
    for (int blk = blockIdx.x; blk < 3072; blk += gridDim.x) {
      const int idx = blk * 256 + tid;
      if (idx < 262144) {                      // dec: [4][128][512]
        const int d = (idx >> 9) & 127;
        float v = kG1 * dterm[idx];
        if (d > 0)   v += kG0 * dterm[idx - 512];
        if (d < 127) v += kG0 * dterm[idx + 512];
        dec_blur[idx] = v;
      } else {                                  // enc: [4][256][512]
        const int j = idx - 262144;
        const int e = (j >> 9) & 255;
        float v = kG1 * term[j];
        if (e > 0)   v += kG0 * term[j - 512];
        if (e < 255) v += kG0 * term[j + 512];
        enc_blur[j] = v;
      }
    }
  }
  grid.sync();

  // ===== phase 4a: grid assembly (256 MB write) =====
  {
    const float* dterm = term + 524288;
    const int eo = tid >> 7;
    const int o4 = (tid & 127) << 2;
    for (int u = blockIdx.x; u < 2048; u += gridDim.x) {
      const int bd = u >> 2;
      const int b = bd >> 7;
      const int ebase = (u & 3) * 64;
      const float4 dv = *(const float4*)(dterm + (size_t)bd * 512 + o4);
      const float4 bv = *(const float4*)(b_fus + o4);
      const float4 db = make_float4(dv.x + bv.x, dv.y + bv.y, dv.z + bv.z, dv.w + bv.w);
      const float* encb = term + (size_t)b * 256 * 512;
      float* outb = out + (size_t)bd * 256 * 512;
#pragma unroll 4
      for (int e0 = 0; e0 < 64; e0 += 2) {
        const int e = ebase + e0 + eo;
        const float4 ev = *(const float4*)(encb + (size_t)e * 512 + o4);
        *(float4*)(outb + (size_t)e * 512 + o4) =
            make_float4(db.x + ev.x, db.y + ev.y, db.z + ev.z, db.w + ev.w);
      }
    }
  }

  // ===== phase 4b: mask (concurrent with 4a; disjoint output region) =====
  {
    float* mask_out = out + (size_t)4 * 128 * 256 * 512;
    for (int g = blockIdx.x; g < 32768; g += gridDim.x) {
      const int bid = g * 4 + wid;             // (b*128 + d)*256 + e
      const int e = bid & 255;
      const int d = (bid >> 8) & 127;
      const int b = bid >> 15;
      const float sE  = (e == 0 || e == 255) ? kEdge : 1.f;
      const float sD  = (d == 0 || d == 127) ? kEdge : 1.f;
      const float sED = sE * sD;
      const float* dp = dec_blur + ((size_t)(b * 128 + d)) * 512 + lane * 8;
      const float* ep = enc_blur + ((size_t)(b * 256 + e)) * 512 + lane * 8;
      const float* zp = b_fus + lane * 8;
      float acc = 0.f;
#pragma unroll
      for (int j = 0; j < 2; ++j) {
        const float4 dv = *(const float4*)(dp + 4 * j);
        const float4 ev = *(const float4*)(ep + 4 * j);
        const float4 zv = *(const float4*)(zp + 4 * j);
        float tt;
        tt = dv.x * sE + ev.x * sD + zv.x * sED; acc += tt * tt;
        tt = dv.y * sE + ev.y * sD + zv.y * sED; acc += tt * tt;
        tt = dv.z * sE + ev.z * sD + zv.z * sED; acc += tt * tt;
        tt = dv.w * sE + ev.w * sD + zv.w * sED; acc += tt * tt;
      }
#pragma unroll
      for (int off = 32; off; off >>= 1) acc += __shfl_down(acc, off);
      if (!lane) mask_out[bid] = (acc > 0.f) ? 1.f : 0.f;
    }
  }
}

}  // namespace

extern "C" void kernel_launch(void* const* d_in, const int* in_sizes, int n_in,
                              void* d_out, int out_size, void* d_ws, size_t ws_size,
                              hipStream_t stream) {
  const float* enc_h = (const float*)d_in[0];
  const float* dec_h = (const float*)d_in[1];
  const float* enc_m = (const float*)d_in[2];
  const float* dec_m = (const float*)d_in[3];
  const float* W_enc = (const float*)d_in[4];
  const float* b_enc = (const float*)d_in[5];
  const float* W_dec = (const float*)d_in[6];
  const float* b_dec = (const float*)d_in[7];
  const float* W_fus = (const float*)d_in[8];
  const float* b_fus = (const float*)d_in[9];
  float* out = (float*)d_out;
  float* ws  = (float*)d_ws;

  // ws layout (floats): term[786432] | proj(ushort)[786432]=393216f |
  //                     dec_blur[262144] | enc_blur[524288]  -> 7.9 MB total
  float*  term     = ws;
  ushort* proj     = (ushort*)(ws + 786432);
  float*  dec_blur = ws + 786432 + 393216;
  float*  enc_blur = dec_blur + 262144;

  int dev = 0;
  (void)hipGetDevice(&dev);
  int cus = 256;
  (void)hipDeviceGetAttribute(&cus, hipDeviceAttributeMultiprocessorCount, dev);
  if (cus <= 0) cus = 256;
  int maxb = 3;
  (void)hipOccupancyMaxActiveBlocksPerMultiprocessor(&maxb, (const void*)fused, 256, 0);
  if (maxb < 1) maxb = 1;
  long nb = (long)cus * (long)maxb;
  if (nb > 2048) nb = 2048;
  if (nb < 8) nb = 8;

  void* args[] = {(void*)&enc_h, (void*)&dec_h, (void*)&enc_m, (void*)&dec_m,
                  (void*)&W_enc, (void*)&b_enc, (void*)&W_dec, (void*)&b_dec,
                  (void*)&W_fus, (void*)&b_fus, (void*)&out, (void*)&proj,
                  (void*)&term, (void*)&dec_blur, (void*)&enc_blur};
  (void)hipLaunchCooperativeKernel((const void*)fused, dim3((unsigned)nb), dim3(256),
                                   args, 0, stream);
}